// Round 7
// baseline (385.155 us; speedup 1.0000x reference)
//
#include <hip/hip_runtime.h>

// Problem: B=1, S=8192, D=4096, D_OUT=4096, FP=256, BITS=4 (MAXQ=15)
// out = mixed @ W^T + bias; mixed = per-row-4bit-quant(x) on q cols, x on fp cols.
// Pipeline: prep (fused quant+wconv, flags built in LDS) -> 256^2 MFMA GEMM.
// GEMM = R3 schedule (best: 249us, MfmaUtil 49%) + K-loop unroll x2 so the
// double-buffer offset is a compile-time constant (LDS addr -> immediates).

typedef __attribute__((ext_vector_type(8))) short short8;
typedef __attribute__((ext_vector_type(4))) float f32x4;

#define S_ROWS 8192
#define D_IN   4096
#define D_OUTC 4096
#define MAXQF  15.0f

__device__ __forceinline__ unsigned short f2bf(float f) {
  unsigned int u = __float_as_uint(f);
  u += 0x7FFFu + ((u >> 16) & 1u);   // RNE (no NaN in data)
  return (unsigned short)(u >> 16);
}

// ---- kernel 1: fused prep ----
// blocks [0, S_ROWS)            : per-row quantize+mix (flags built in LDS)
// blocks [S_ROWS, S_ROWS+8192)  : weight fp32 -> bf16
__global__ __launch_bounds__(256) void prep_kernel(const float* __restrict__ x,
                                                   const float* __restrict__ W,
                                                   const int* __restrict__ fp_idx,
                                                   short* __restrict__ mixed,
                                                   short* __restrict__ Wb) {
  const int bid = blockIdx.x;
  const int t = threadIdx.x;

  if (bid >= S_ROWS) {
    // ---- wconv: 256 thr x 8 elems ----
    const size_t i = ((size_t)(bid - S_ROWS) * 256 + t) * 8;
    float4 a = *(const float4*)(W + i);
    float4 b = *(const float4*)(W + i + 4);
    short8 o;
    o[0] = (short)f2bf(a.x); o[1] = (short)f2bf(a.y);
    o[2] = (short)f2bf(a.z); o[3] = (short)f2bf(a.w);
    o[4] = (short)f2bf(b.x); o[5] = (short)f2bf(b.y);
    o[6] = (short)f2bf(b.z); o[7] = (short)f2bf(b.w);
    *(short8*)(Wb + i) = o;
    return;
  }

  // ---- quant: one block per row ----
  __shared__ unsigned char fl[4096];   // 1 = fp (passthrough), 0 = quantized
  __shared__ float s_mn[4], s_mx[4];
  ((int4*)fl)[t] = make_int4(0, 0, 0, 0);   // 256 x 16B = 4096
  __syncthreads();
  fl[fp_idx[t]] = 1;                        // 256 threads == FP_FEATURES
  __syncthreads();

  const int row = bid;
  const float* xr = x + (size_t)row * D_IN;

  float4 v[4];
  unsigned int fw[4];
  float mn = 0.0f, mx = 0.0f;   // init at 0 == reference's min(.,0)/max(.,0)
#pragma unroll
  for (int i = 0; i < 4; ++i) {
    const int idx = i * 256 + t;            // float4 index; cols idx*4..idx*4+3
    v[i] = ((const float4*)xr)[idx];
    fw[i] = ((const unsigned int*)fl)[idx];
    if (!(fw[i] & 0x000000FFu)) { mn = fminf(mn, v[i].x); mx = fmaxf(mx, v[i].x); }
    if (!(fw[i] & 0x0000FF00u)) { mn = fminf(mn, v[i].y); mx = fmaxf(mx, v[i].y); }
    if (!(fw[i] & 0x00FF0000u)) { mn = fminf(mn, v[i].z); mx = fmaxf(mx, v[i].z); }
    if (!(fw[i] & 0xFF000000u)) { mn = fminf(mn, v[i].w); mx = fmaxf(mx, v[i].w); }
  }
#pragma unroll
  for (int d = 32; d > 0; d >>= 1) {
    mn = fminf(mn, __shfl_xor(mn, d));
    mx = fmaxf(mx, __shfl_xor(mx, d));
  }
  if ((t & 63) == 0) { s_mn[t >> 6] = mn; s_mx[t >> 6] = mx; }
  __syncthreads();
  mn = fminf(fminf(s_mn[0], s_mn[1]), fminf(s_mn[2], s_mn[3]));
  mx = fmaxf(fmaxf(s_mx[0], s_mx[1]), fmaxf(s_mx[2], s_mx[3]));
  if (mn == 0.0f && mx == 0.0f) { mn = -1.0f; mx = 1.0f; }
  const float scale = (mx - mn) / MAXQF;    // exact IEEE div, matches np
  const float zp = rintf(-mn / scale);      // rintf == np round-half-even

  short* mr = mixed + (size_t)row * D_IN;
#pragma unroll
  for (int i = 0; i < 4; ++i) {
    const int idx = i * 256 + t;
    const float in[4] = { v[i].x, v[i].y, v[i].z, v[i].w };
    const unsigned int f = fw[i];
    float o[4];
#pragma unroll
    for (int j = 0; j < 4; ++j) {
      const float val = in[j];
      float q = fminf(fmaxf(rintf(val / scale) + zp, 0.0f), MAXQF);
      float dq = scale * (q - zp);
      o[j] = ((f >> (8 * j)) & 0xFFu) ? val : dq;
    }
    short4 s;
    s.x = (short)f2bf(o[0]); s.y = (short)f2bf(o[1]);
    s.z = (short)f2bf(o[2]); s.w = (short)f2bf(o[3]);
    ((short4*)mr)[idx] = s;
  }
}

// ---------------------------------------------------------------------------
// kernel 2: 256x256-tile, BK=64, 8-wave, 4 phases/K-tile (R3 schedule).
// Stage: P1/P2 = B(t+1), P3/P4 = A(t+2); counted vmcnt(4) once per K-tile.
// K-loop unrolled x2: double-buffer offset BO is a compile-time constant.
// ---------------------------------------------------------------------------

__device__ __forceinline__ void gl2lds16(const short* g, const short* l) {
  __builtin_amdgcn_global_load_lds(
      (const __attribute__((address_space(1))) unsigned int*)g,
      (__attribute__((address_space(3))) unsigned int*)l, 16, 0, 0);
}

#define BARRIER()  asm volatile("s_barrier" ::: "memory")
#define LGKM0()    do { asm volatile("s_waitcnt lgkmcnt(0)" ::: "memory"); \
                        __builtin_amdgcn_sched_barrier(0); } while (0)

__global__ __launch_bounds__(512) void gemm256_kernel(const short* __restrict__ A,
                                                      const short* __restrict__ Bw,
                                                      const float* __restrict__ bias,
                                                      float* __restrict__ C) {
  // LDS: [buf(2)][half(4): A0,A1,B0,B1][8192 shorts (128 rows x 64 cols)]
  __shared__ __align__(16) short lds[65536];   // 128 KiB
  const int tid = threadIdx.x;
  const int l   = tid & 63;
  const int w   = tid >> 6;          // 0..7
  const int wr  = w >> 2;            // 0..1 (M half)
  const int wc  = w & 3;             // 0..3 (N quarter)

  // XCD-bijective swizzle (R3, proven): 512 wgs, 8 XCDs, 64 contiguous per XCD
  const int bid = blockIdx.x;
  const int swz = (bid & 7) * 64 + (bid >> 3);
  const int bm  = swz >> 4;          // 0..31
  const int bn  = swz & 15;          // 0..15

  // ---- staging geometry (rule #21: linear LDS dest + inverse-swizzled
  //      per-lane global source; reads apply the same XOR) ----
  const int c16  = ((l & 7) ^ (l >> 3)) * 8;        // source chunk (shorts)
  const int rib0 = (w * 2 + 0) * 8 + (l >> 3);
  const int rib1 = (w * 2 + 1) * 8 + (l >> 3);
  const int d0   = (w * 2 + 0) * 512;               // LDS dest base (shorts)
  const int d1   = (w * 2 + 1) * 512;

  const short* bA00 = A  + (size_t)(bm * 256 +   0 + rib0) * D_IN + c16;
  const short* bA01 = A  + (size_t)(bm * 256 +   0 + rib1) * D_IN + c16;
  const short* bA10 = A  + (size_t)(bm * 256 + 128 + rib0) * D_IN + c16;
  const short* bA11 = A  + (size_t)(bm * 256 + 128 + rib1) * D_IN + c16;
  const short* bB00 = Bw + (size_t)(bn * 256 +   0 + rib0) * D_IN + c16;
  const short* bB01 = Bw + (size_t)(bn * 256 +   0 + rib1) * D_IN + c16;
  const short* bB10 = Bw + (size_t)(bn * 256 + 128 + rib0) * D_IN + c16;
  const short* bB11 = Bw + (size_t)(bn * 256 + 128 + rib1) * D_IN + c16;

  // ---- prologue: stage Kt0 {A0,A1,B0,B1} -> buf0, Kt1 {A0,A1} -> buf1 ----
  gl2lds16(bA00, &lds[0 + d0]);          gl2lds16(bA01, &lds[0 + d1]);
  gl2lds16(bA10, &lds[8192 + d0]);       gl2lds16(bA11, &lds[8192 + d1]);
  gl2lds16(bB00, &lds[16384 + d0]);      gl2lds16(bB01, &lds[16384 + d1]);
  gl2lds16(bB10, &lds[24576 + d0]);      gl2lds16(bB11, &lds[24576 + d1]);
  gl2lds16(bA00 + 64, &lds[32768 + d0]); gl2lds16(bA01 + 64, &lds[32768 + d1]);
  gl2lds16(bA10 + 64, &lds[40960 + d0]); gl2lds16(bA11 + 64, &lds[40960 + d1]);
  asm volatile("s_waitcnt vmcnt(4)" ::: "memory");   // Kt0 fully landed
  BARRIER();

  // running stage pointers: A at ktile 2, B at ktile 1 (shorts; +64/ktile)
  const short* pA00 = bA00 + 128; const short* pA01 = bA01 + 128;
  const short* pA10 = bA10 + 128; const short* pA11 = bA11 + 128;
  const short* pB00 = bB00 + 64;  const short* pB01 = bB01 + 64;
  const short* pB10 = bB10 + 64;  const short* pB11 = bB11 + 64;

  // ---- read-side fragment offsets (shorts) ----
  const int ch0  = ((l >> 4) ^ (l & 7)) * 8;              // ks=0 ; ks=1 -> ^32
  const int aoff = wr * 8192 + (l & 15) * 64;             // + m*1024 + ch
  const int boff = 16384 + (wc >> 1) * 8192 + (wc & 1) * 4096 + (l & 15) * 64;

  f32x4 acc[8][4] = {};

#define KSTEP(BO, T)                                                          \
  do {                                                                        \
    short8 a0[4][2], a1[4][2], b[2][2];                                       \
    /* P1: read a[0-3], b[0-1]; stage B0(t+1) */                              \
    _Pragma("unroll")                                                         \
    for (int m = 0; m < 4; ++m) {                                             \
      a0[m][0] = *(const short8*)&lds[(BO) + aoff + m * 1024 + ch0];          \
      a0[m][1] = *(const short8*)&lds[(BO) + aoff + m * 1024 + (ch0 ^ 32)];   \
    }                                                                         \
    _Pragma("unroll")                                                         \
    for (int n = 0; n < 2; ++n) {                                             \
      b[n][0] = *(const short8*)&lds[(BO) + boff + n * 1024 + ch0];           \
      b[n][1] = *(const short8*)&lds[(BO) + boff + n * 1024 + (ch0 ^ 32)];    \
    }                                                                         \
    if ((T) < 63) { gl2lds16(pB00, &lds[((BO) ^ 32768) + 16384 + d0]);        \
                    gl2lds16(pB01, &lds[((BO) ^ 32768) + 16384 + d1]); }      \
    asm volatile("s_waitcnt lgkmcnt(8)" ::: "memory");                        \
    BARRIER();                                                                \
    LGKM0();                                                                  \
    __builtin_amdgcn_s_setprio(1);                                            \
    _Pragma("unroll")                                                         \
    for (int m = 0; m < 4; ++m)                                               \
      _Pragma("unroll")                                                       \
      for (int n = 0; n < 2; ++n) {                                           \
        acc[m][n] = __builtin_amdgcn_mfma_f32_16x16x32_bf16(a0[m][0], b[n][0], acc[m][n], 0, 0, 0); \
        acc[m][n] = __builtin_amdgcn_mfma_f32_16x16x32_bf16(a0[m][1], b[n][1], acc[m][n], 0, 0, 0); \
      }                                                                       \
    __builtin_amdgcn_s_setprio(0);                                            \
    BARRIER();                                                                \
    /* P2: read a[4-7]; stage B1(t+1) */                                      \
    _Pragma("unroll")                                                         \
    for (int m = 0; m < 4; ++m) {                                             \
      a1[m][0] = *(const short8*)&lds[(BO) + aoff + (m + 4) * 1024 + ch0];    \
      a1[m][1] = *(const short8*)&lds[(BO) + aoff + (m + 4) * 1024 + (ch0 ^ 32)]; \
    }                                                                         \
    if ((T) < 63) { gl2lds16(pB10, &lds[((BO) ^ 32768) + 24576 + d0]);        \
                    gl2lds16(pB11, &lds[((BO) ^ 32768) + 24576 + d1]); }      \
    BARRIER();                                                                \
    LGKM0();                                                                  \
    __builtin_amdgcn_s_setprio(1);                                            \
    _Pragma("unroll")                                                         \
    for (int m = 0; m < 4; ++m)                                               \
      _Pragma("unroll")                                                       \
      for (int n = 0; n < 2; ++n) {                                           \
        acc[m + 4][n] = __builtin_amdgcn_mfma_f32_16x16x32_bf16(a1[m][0], b[n][0], acc[m + 4][n], 0, 0, 0); \
        acc[m + 4][n] = __builtin_amdgcn_mfma_f32_16x16x32_bf16(a1[m][1], b[n][1], acc[m + 4][n], 0, 0, 0); \
      }                                                                       \
    __builtin_amdgcn_s_setprio(0);                                            \
    BARRIER();                                                                \
    /* P3: read b[2-3]; stage A0(t+2) (A(t) dead since end-P2) */             \
    _Pragma("unroll")                                                         \
    for (int n = 0; n < 2; ++n) {                                             \
      b[n][0] = *(const short8*)&lds[(BO) + boff + (n + 2) * 1024 + ch0];     \
      b[n][1] = *(const short8*)&lds[(BO) + boff + (n + 2) * 1024 + (ch0 ^ 32)]; \
    }                                                                         \
    if ((T) < 62) { gl2lds16(pA00, &lds[(BO) + 0 + d0]);                      \
                    gl2lds16(pA01, &lds[(BO) + 0 + d1]); }                    \
    BARRIER();                                                                \
    LGKM0();                                                                  \
    __builtin_amdgcn_s_setprio(1);                                            \
    _Pragma("unroll")                                                         \
    for (int m = 0; m < 4; ++m)                                               \
      _Pragma("unroll")                                                       \
      for (int n = 0; n < 2; ++n) {                                           \
        acc[m + 4][n + 2] = __builtin_amdgcn_mfma_f32_16x16x32_bf16(a1[m][0], b[n][0], acc[m + 4][n + 2], 0, 0, 0); \
        acc[m + 4][n + 2] = __builtin_amdgcn_mfma_f32_16x16x32_bf16(a1[m][1], b[n][1], acc[m + 4][n + 2], 0, 0, 0); \
      }                                                                       \
    __builtin_amdgcn_s_setprio(0);                                            \
    BARRIER();                                                                \
    /* P4: stage A1(t+2); reg-only MFMA; counted vmcnt */                     \
    if ((T) < 62) { gl2lds16(pA10, &lds[(BO) + 8192 + d0]);                   \
                    gl2lds16(pA11, &lds[(BO) + 8192 + d1]); }                 \
    BARRIER();                                                                \
    __builtin_amdgcn_s_setprio(1);                                            \
    _Pragma("unroll")                                                         \
    for (int m = 0; m < 4; ++m)                                               \
      _Pragma("unroll")                                                       \
      for (int n = 0; n < 2; ++n) {                                           \
        acc[m][n + 2] = __builtin_amdgcn_mfma_f32_16x16x32_bf16(a0[m][0], b[n][0], acc[m][n + 2], 0, 0, 0); \
        acc[m][n + 2] = __builtin_amdgcn_mfma_f32_16x16x32_bf16(a0[m][1], b[n][1], acc[m][n + 2], 0, 0, 0); \
      }                                                                       \
    __builtin_amdgcn_s_setprio(0);                                            \
    if ((T) < 62) { asm volatile("s_waitcnt vmcnt(4)" ::: "memory"); }        \
    else          { asm volatile("s_waitcnt vmcnt(0)" ::: "memory"); }        \
    BARRIER();                                                                \
    pA00 += 64; pA01 += 64; pA10 += 64; pA11 += 64;                           \
    pB00 += 64; pB01 += 64; pB10 += 64; pB11 += 64;                           \
  } while (0)

  for (int tt = 0; tt < 32; ++tt) {
    KSTEP(0, tt * 2);
    KSTEP(32768, tt * 2 + 1);
  }
#undef KSTEP

  // ---- epilogue: C/D layout col=lane&15, row=(lane>>4)*4+reg ----
  const int row0 = bm * 256 + wr * 128 + ((l >> 4) << 2);
  const int col0 = bn * 256 + wc * 64 + (l & 15);
#pragma unroll
  for (int m = 0; m < 8; ++m)
#pragma unroll
    for (int n = 0; n < 4; ++n) {
      const int col = col0 + n * 16;
      const float bv = bias[col];
#pragma unroll
      for (int r = 0; r < 4; ++r)
        C[(size_t)(row0 + m * 16 + r) * D_OUTC + col] = acc[m][n][r] + bv;
    }
}

extern "C" void kernel_launch(void* const* d_in, const int* in_sizes, int n_in,
                              void* d_out, int out_size, void* d_ws, size_t ws_size,
                              hipStream_t stream) {
  const float* x    = (const float*)d_in[0];
  const float* W    = (const float*)d_in[1];
  const float* bias = (const float*)d_in[2];
  const int* fp_idx = (const int*)d_in[4];   // int32 (harness demotes int64)

  short* mixed = (short*)d_ws;
  short* Wb    = (short*)((char*)d_ws + (size_t)S_ROWS * D_IN * 2);
  float* out = (float*)d_out;

  // quant rows (8192 blocks) + wconv (8192 blocks) in one launch
  prep_kernel<<<S_ROWS + 8192, 256, 0, stream>>>(x, W, fp_idx, mixed, Wb);
  gemm256_kernel<<<(S_ROWS / 256) * (D_OUTC / 256), 512, 0, stream>>>(mixed, Wb, bias, out);
}

// Round 8
// 287.588 us; speedup vs baseline: 1.3393x; 1.3393x over previous
//
#include <hip/hip_runtime.h>

// Problem: B=1, S=8192, D=4096, D_OUT=4096, FP=256, BITS=4 (MAXQ=15)
// out = mixed @ W^T + bias; mixed = per-row-4bit-quant(x) on q cols, x on fp cols.
// Pipeline: prep (fused quant+wconv, flags in LDS) -> 256^2 MFMA GEMM.
// GEMM = R3 kernel verbatim (best: 249us, MfmaUtil 49%, 0 bank conflicts).
// R7 lesson: x2 K-loop unroll blew I-cache (FETCH +95MB, MfmaUtil 49->32) — rolled loop only.

typedef __attribute__((ext_vector_type(8))) short short8;
typedef __attribute__((ext_vector_type(4))) float f32x4;

#define S_ROWS 8192
#define D_IN   4096
#define D_OUTC 4096
#define MAXQF  15.0f

__device__ __forceinline__ unsigned short f2bf(float f) {
  unsigned int u = __float_as_uint(f);
  u += 0x7FFFu + ((u >> 16) & 1u);   // RNE (no NaN in data)
  return (unsigned short)(u >> 16);
}

// ---- kernel 1: fused prep ----
// blocks [0, S_ROWS)            : per-row quantize+mix (flags built in LDS)
// blocks [S_ROWS, S_ROWS+8192)  : weight fp32 -> bf16
__global__ __launch_bounds__(256) void prep_kernel(const float* __restrict__ x,
                                                   const float* __restrict__ W,
                                                   const int* __restrict__ fp_idx,
                                                   short* __restrict__ mixed,
                                                   short* __restrict__ Wb) {
  const int bid = blockIdx.x;
  const int t = threadIdx.x;

  if (bid >= S_ROWS) {
    // ---- wconv: 256 thr x 8 elems ----
    const size_t i = ((size_t)(bid - S_ROWS) * 256 + t) * 8;
    float4 a = *(const float4*)(W + i);
    float4 b = *(const float4*)(W + i + 4);
    short8 o;
    o[0] = (short)f2bf(a.x); o[1] = (short)f2bf(a.y);
    o[2] = (short)f2bf(a.z); o[3] = (short)f2bf(a.w);
    o[4] = (short)f2bf(b.x); o[5] = (short)f2bf(b.y);
    o[6] = (short)f2bf(b.z); o[7] = (short)f2bf(b.w);
    *(short8*)(Wb + i) = o;
    return;
  }

  // ---- quant: one block per row ----
  __shared__ unsigned char fl[4096];   // 1 = fp (passthrough), 0 = quantized
  __shared__ float s_mn[4], s_mx[4];
  ((int4*)fl)[t] = make_int4(0, 0, 0, 0);   // 256 x 16B = 4096
  __syncthreads();
  fl[fp_idx[t]] = 1;                        // 256 threads == FP_FEATURES
  __syncthreads();

  const int row = bid;
  const float* xr = x + (size_t)row * D_IN;

  float4 v[4];
  unsigned int fw[4];
  float mn = 0.0f, mx = 0.0f;   // init at 0 == reference's min(.,0)/max(.,0)
#pragma unroll
  for (int i = 0; i < 4; ++i) {
    const int idx = i * 256 + t;            // float4 index; cols idx*4..idx*4+3
    v[i] = ((const float4*)xr)[idx];
    fw[i] = ((const unsigned int*)fl)[idx];
    if (!(fw[i] & 0x000000FFu)) { mn = fminf(mn, v[i].x); mx = fmaxf(mx, v[i].x); }
    if (!(fw[i] & 0x0000FF00u)) { mn = fminf(mn, v[i].y); mx = fmaxf(mx, v[i].y); }
    if (!(fw[i] & 0x00FF0000u)) { mn = fminf(mn, v[i].z); mx = fmaxf(mx, v[i].z); }
    if (!(fw[i] & 0xFF000000u)) { mn = fminf(mn, v[i].w); mx = fmaxf(mx, v[i].w); }
  }
#pragma unroll
  for (int d = 32; d > 0; d >>= 1) {
    mn = fminf(mn, __shfl_xor(mn, d));
    mx = fmaxf(mx, __shfl_xor(mx, d));
  }
  if ((t & 63) == 0) { s_mn[t >> 6] = mn; s_mx[t >> 6] = mx; }
  __syncthreads();
  mn = fminf(fminf(s_mn[0], s_mn[1]), fminf(s_mn[2], s_mn[3]));
  mx = fmaxf(fmaxf(s_mx[0], s_mx[1]), fmaxf(s_mx[2], s_mx[3]));
  if (mn == 0.0f && mx == 0.0f) { mn = -1.0f; mx = 1.0f; }
  const float scale = (mx - mn) / MAXQF;    // exact IEEE div, matches np
  const float zp = rintf(-mn / scale);      // rintf == np round-half-even

  short* mr = mixed + (size_t)row * D_IN;
#pragma unroll
  for (int i = 0; i < 4; ++i) {
    const int idx = i * 256 + t;
    const float in[4] = { v[i].x, v[i].y, v[i].z, v[i].w };
    const unsigned int f = fw[i];
    float o[4];
#pragma unroll
    for (int j = 0; j < 4; ++j) {
      const float val = in[j];
      float q = fminf(fmaxf(rintf(val / scale) + zp, 0.0f), MAXQF);
      float dq = scale * (q - zp);
      o[j] = ((f >> (8 * j)) & 0xFFu) ? val : dq;
    }
    short4 s;
    s.x = (short)f2bf(o[0]); s.y = (short)f2bf(o[1]);
    s.z = (short)f2bf(o[2]); s.w = (short)f2bf(o[3]);
    ((short4*)mr)[idx] = s;
  }
}

// ---------------------------------------------------------------------------
// kernel 2: 256x256-tile, BK=64, 8-wave, 4 phases/K-tile (R3 schedule,
// verbatim). Stage: P1/P2 = B(t+1), P3/P4 = A(t+2); vmcnt(4) once per K-tile.
// ---------------------------------------------------------------------------

__device__ __forceinline__ void gl2lds16(const short* g, const short* l) {
  __builtin_amdgcn_global_load_lds(
      (const __attribute__((address_space(1))) unsigned int*)g,
      (__attribute__((address_space(3))) unsigned int*)l, 16, 0, 0);
}

#define BARRIER()  asm volatile("s_barrier" ::: "memory")
#define LGKM0()    do { asm volatile("s_waitcnt lgkmcnt(0)" ::: "memory"); \
                        __builtin_amdgcn_sched_barrier(0); } while (0)

__global__ __launch_bounds__(512) void gemm256_kernel(const short* __restrict__ A,
                                                      const short* __restrict__ Bw,
                                                      const float* __restrict__ bias,
                                                      float* __restrict__ C) {
  // LDS: [buf(2)][half(4): A0,A1,B0,B1][8192 shorts (128 rows x 64 cols)]
  __shared__ __align__(16) short lds[65536];   // 128 KiB
  const int tid = threadIdx.x;
  const int l   = tid & 63;
  const int w   = tid >> 6;          // 0..7
  const int wr  = w >> 2;            // 0..1 (M half)
  const int wc  = w & 3;             // 0..3 (N quarter)

  // XCD-bijective swizzle: 512 wgs, 8 XCDs, 64 contiguous per XCD
  const int bid = blockIdx.x;
  const int swz = (bid & 7) * 64 + (bid >> 3);
  const int bm  = swz >> 4;          // 0..31
  const int bn  = swz & 15;          // 0..15

  // ---- staging geometry (rule #21: linear LDS dest + inverse-swizzled
  //      per-lane global source; reads apply the same XOR) ----
  const int c16  = ((l & 7) ^ (l >> 3)) * 8;        // source chunk (shorts)
  const int rib0 = (w * 2 + 0) * 8 + (l >> 3);
  const int rib1 = (w * 2 + 1) * 8 + (l >> 3);
  const int d0   = (w * 2 + 0) * 512;               // LDS dest base (shorts)
  const int d1   = (w * 2 + 1) * 512;

  const short* bA00 = A  + (size_t)(bm * 256 +   0 + rib0) * D_IN + c16;
  const short* bA01 = A  + (size_t)(bm * 256 +   0 + rib1) * D_IN + c16;
  const short* bA10 = A  + (size_t)(bm * 256 + 128 + rib0) * D_IN + c16;
  const short* bA11 = A  + (size_t)(bm * 256 + 128 + rib1) * D_IN + c16;
  const short* bB00 = Bw + (size_t)(bn * 256 +   0 + rib0) * D_IN + c16;
  const short* bB01 = Bw + (size_t)(bn * 256 +   0 + rib1) * D_IN + c16;
  const short* bB10 = Bw + (size_t)(bn * 256 + 128 + rib0) * D_IN + c16;
  const short* bB11 = Bw + (size_t)(bn * 256 + 128 + rib1) * D_IN + c16;

  // ---- prologue: stage Kt0 {A0,A1,B0,B1} -> buf0, Kt1 {A0,A1} -> buf1 ----
  gl2lds16(bA00, &lds[0 + d0]);          gl2lds16(bA01, &lds[0 + d1]);
  gl2lds16(bA10, &lds[8192 + d0]);       gl2lds16(bA11, &lds[8192 + d1]);
  gl2lds16(bB00, &lds[16384 + d0]);      gl2lds16(bB01, &lds[16384 + d1]);
  gl2lds16(bB10, &lds[24576 + d0]);      gl2lds16(bB11, &lds[24576 + d1]);
  gl2lds16(bA00 + 64, &lds[32768 + d0]); gl2lds16(bA01 + 64, &lds[32768 + d1]);
  gl2lds16(bA10 + 64, &lds[40960 + d0]); gl2lds16(bA11 + 64, &lds[40960 + d1]);
  asm volatile("s_waitcnt vmcnt(4)" ::: "memory");   // Kt0 fully landed
  BARRIER();

  // running stage pointers: A at ktile 2, B at ktile 1 (shorts; +64/ktile)
  const short* pA00 = bA00 + 128; const short* pA01 = bA01 + 128;
  const short* pA10 = bA10 + 128; const short* pA11 = bA11 + 128;
  const short* pB00 = bB00 + 64;  const short* pB01 = bB01 + 64;
  const short* pB10 = bB10 + 64;  const short* pB11 = bB11 + 64;

  // ---- read-side fragment offsets (shorts) ----
  const int ch0  = ((l >> 4) ^ (l & 7)) * 8;              // ks=0 ; ks=1 -> ^32
  const int aoff = wr * 8192 + (l & 15) * 64;             // + m*1024 + ch
  const int boff = 16384 + (wc >> 1) * 8192 + (wc & 1) * 4096 + (l & 15) * 64;

  f32x4 acc[8][4] = {};
  int bo = 0;   // LDS offset of current K-tile's buffer

  for (int t = 0; t < 64; ++t) {
    const int nxt = bo ^ 32768;
    short8 a0[4][2], a1[4][2], b[2][2];

    // ======== P1: read a[0-3], b[0-1]; stage B0(t+1) ========
#pragma unroll
    for (int m = 0; m < 4; ++m) {
      a0[m][0] = *(const short8*)&lds[bo + aoff + m * 1024 + ch0];
      a0[m][1] = *(const short8*)&lds[bo + aoff + m * 1024 + (ch0 ^ 32)];
    }
#pragma unroll
    for (int n = 0; n < 2; ++n) {
      b[n][0] = *(const short8*)&lds[bo + boff + n * 1024 + ch0];
      b[n][1] = *(const short8*)&lds[bo + boff + n * 1024 + (ch0 ^ 32)];
    }
    if (t < 63) { gl2lds16(pB00, &lds[nxt + 16384 + d0]);
                  gl2lds16(pB01, &lds[nxt + 16384 + d1]); }
    asm volatile("s_waitcnt lgkmcnt(8)" ::: "memory");
    BARRIER();
    LGKM0();
    __builtin_amdgcn_s_setprio(1);
#pragma unroll
    for (int m = 0; m < 4; ++m)
#pragma unroll
      for (int n = 0; n < 2; ++n) {
        acc[m][n] = __builtin_amdgcn_mfma_f32_16x16x32_bf16(a0[m][0], b[n][0], acc[m][n], 0, 0, 0);
        acc[m][n] = __builtin_amdgcn_mfma_f32_16x16x32_bf16(a0[m][1], b[n][1], acc[m][n], 0, 0, 0);
      }
    __builtin_amdgcn_s_setprio(0);
    BARRIER();

    // ======== P2: read a[4-7]; stage B1(t+1) ========
#pragma unroll
    for (int m = 0; m < 4; ++m) {
      a1[m][0] = *(const short8*)&lds[bo + aoff + (m + 4) * 1024 + ch0];
      a1[m][1] = *(const short8*)&lds[bo + aoff + (m + 4) * 1024 + (ch0 ^ 32)];
    }
    if (t < 63) { gl2lds16(pB10, &lds[nxt + 24576 + d0]);
                  gl2lds16(pB11, &lds[nxt + 24576 + d1]); }
    BARRIER();
    LGKM0();
    __builtin_amdgcn_s_setprio(1);
#pragma unroll
    for (int m = 0; m < 4; ++m)
#pragma unroll
      for (int n = 0; n < 2; ++n) {
        acc[m + 4][n] = __builtin_amdgcn_mfma_f32_16x16x32_bf16(a1[m][0], b[n][0], acc[m + 4][n], 0, 0, 0);
        acc[m + 4][n] = __builtin_amdgcn_mfma_f32_16x16x32_bf16(a1[m][1], b[n][1], acc[m + 4][n], 0, 0, 0);
      }
    __builtin_amdgcn_s_setprio(0);
    BARRIER();

    // ======== P3: read b[2-3]; stage A0(t+2) (A(t) dead since end-P2) ==
#pragma unroll
    for (int n = 0; n < 2; ++n) {
      b[n][0] = *(const short8*)&lds[bo + boff + (n + 2) * 1024 + ch0];
      b[n][1] = *(const short8*)&lds[bo + boff + (n + 2) * 1024 + (ch0 ^ 32)];
    }
    if (t < 62) { gl2lds16(pA00, &lds[bo + 0 + d0]);
                  gl2lds16(pA01, &lds[bo + 0 + d1]); }
    BARRIER();
    LGKM0();
    __builtin_amdgcn_s_setprio(1);
#pragma unroll
    for (int m = 0; m < 4; ++m)
#pragma unroll
      for (int n = 0; n < 2; ++n) {
        acc[m + 4][n + 2] = __builtin_amdgcn_mfma_f32_16x16x32_bf16(a1[m][0], b[n][0], acc[m + 4][n + 2], 0, 0, 0);
        acc[m + 4][n + 2] = __builtin_amdgcn_mfma_f32_16x16x32_bf16(a1[m][1], b[n][1], acc[m + 4][n + 2], 0, 0, 0);
      }
    __builtin_amdgcn_s_setprio(0);
    BARRIER();

    // ======== P4: stage A1(t+2) (A(t) dead); reg-only MFMA; counted vmcnt =
    if (t < 62) { gl2lds16(pA10, &lds[bo + 8192 + d0]);
                  gl2lds16(pA11, &lds[bo + 8192 + d1]); }
    BARRIER();
    __builtin_amdgcn_s_setprio(1);
#pragma unroll
    for (int m = 0; m < 4; ++m)
#pragma unroll
      for (int n = 0; n < 2; ++n) {
        acc[m][n + 2] = __builtin_amdgcn_mfma_f32_16x16x32_bf16(a0[m][0], b[n][0], acc[m][n + 2], 0, 0, 0);
        acc[m][n + 2] = __builtin_amdgcn_mfma_f32_16x16x32_bf16(a0[m][1], b[n][1], acc[m][n + 2], 0, 0, 0);
      }
    __builtin_amdgcn_s_setprio(0);
    // counted drain: leave the 4 newest (A0,A1(t+2)) in flight; drains all
    // of tile t+1 before its P1 reads next iteration.
    if (t < 62) { asm volatile("s_waitcnt vmcnt(4)" ::: "memory"); }
    else        { asm volatile("s_waitcnt vmcnt(0)" ::: "memory"); }
    BARRIER();

    pA00 += 64; pA01 += 64; pA10 += 64; pA11 += 64;
    pB00 += 64; pB01 += 64; pB10 += 64; pB11 += 64;
    bo = nxt;
  }

  // ---- epilogue: C/D layout col=lane&15, row=(lane>>4)*4+reg ----
  const int row0 = bm * 256 + wr * 128 + ((l >> 4) << 2);
  const int col0 = bn * 256 + wc * 64 + (l & 15);
#pragma unroll
  for (int m = 0; m < 8; ++m)
#pragma unroll
    for (int n = 0; n < 4; ++n) {
      const int col = col0 + n * 16;
      const float bv = bias[col];
#pragma unroll
      for (int r = 0; r < 4; ++r)
        C[(size_t)(row0 + m * 16 + r) * D_OUTC + col] = acc[m][n][r] + bv;
    }
}

extern "C" void kernel_launch(void* const* d_in, const int* in_sizes, int n_in,
                              void* d_out, int out_size, void* d_ws, size_t ws_size,
                              hipStream_t stream) {
  const float* x    = (const float*)d_in[0];
  const float* W    = (const float*)d_in[1];
  const float* bias = (const float*)d_in[2];
  const int* fp_idx = (const int*)d_in[4];   // int32 (harness demotes int64)

  short* mixed = (short*)d_ws;
  short* Wb    = (short*)((char*)d_ws + (size_t)S_ROWS * D_IN * 2);
  float* out = (float*)d_out;

  // quant rows (8192 blocks) + wconv (8192 blocks) in one launch
  prep_kernel<<<S_ROWS + 8192, 256, 0, stream>>>(x, W, fp_idx, mixed, Wb);
  gemm256_kernel<<<(S_ROWS / 256) * (D_OUTC / 256), 512, 0, stream>>>(mixed, Wb, bias, out);
}